// Round 19
// baseline (220.291 us; speedup 1.0000x reference)
//
#include <hip/hip_runtime.h>
#include <math.h>

#define N_NODES 50000
#define N_EDGES 600000
#define HID 128
#define FFN_HID 256
#define NEG_SLOPE 0.2f
#define LN_EPS 1e-5f
#define BKT 64            // bucket capacity per node; max degree ~30 for E/N=12 Poisson
#define CSTR 16           // cursor stride (ints): one counter per 64B line

typedef unsigned short u16;
typedef unsigned int u32;
typedef __attribute__((ext_vector_type(8))) short short8;
typedef __attribute__((ext_vector_type(4))) float floatx4;

__device__ __forceinline__ u16 f2bf(float x) {
    unsigned int u = __float_as_uint(x);
    unsigned int r = u + 0x7FFFu + ((u >> 16) & 1u);
    return (u16)(r >> 16);
}
__device__ __forceinline__ float bflo(u32 u) { return __uint_as_float(u << 16); }
__device__ __forceinline__ float bfhi(u32 u) { return __uint_as_float(u & 0xffff0000u); }
__device__ __forceinline__ u32 packbf(float lo, float hi) {
    return (u32)f2bf(lo) | ((u32)f2bf(hi) << 16);
}
__device__ __forceinline__ float bf2f(u16 v) { return __uint_as_float(((u32)v) << 16); }
// tanh-form GELU: max |delta| vs exact erf-GELU ~3e-4; output is bf16-rounded anyway.
__device__ __forceinline__ float gelu_fast(float v) {
    float u = 1.5957691216057308f * fmaf(0.044715f * v * v, v, v);
    return v / (1.0f + __expf(-u));
}

// ---------------- co-launched (3 INTERLEAVED roles): scatter + GEMM1 + W-swizzle ----
// grid = 1738 blocks.
//   gemm (1024):    bid<1536 && bid%3!=2, gid=(bid/3)*2+(bid%3)
//   scatter (586):  bid%3==2 (512) + bid in [1536,1610) (74); 4 edges/thread.
//   swizzle (128):  bid>=1610 — W1/W2 -> B2sw/B3sw fragment tables for ffn.
// Gemm B1 fragments: COOPERATIVE coalesced staging — the block streams
// [Wsrc|Wdst] with sequential float4 loads (L2-resident) and LDS-transposes
// into the bs fragment layout. Each W is 128x128 = 16384 f32 = 16 iters of
// 256 threads x float4 (R18 bug: bound was 32 -> OOB reads + LDS corruption).

__global__ __launch_bounds__(256) void scatter_gemm(
    const int* __restrict__ src, const int* __restrict__ dst,
    int* __restrict__ cursor, u16* __restrict__ ebkt,
    const float* __restrict__ h,
    const float* __restrict__ Wsrc, const float* __restrict__ Wdst,
    const float* __restrict__ bsrc, const float* __restrict__ bdst,
    u16* __restrict__ fsb, u16* __restrict__ fdb,
    const float* __restrict__ W1, const float* __restrict__ W2,
    u16* __restrict__ B2sw, u16* __restrict__ B3sw)
{
    __shared__ u16 bs[4][16][64 * 8];   // [wave][nt*4+ks][lane*8+j] = 64KB (gemm role)
    int bid = blockIdx.x;
    if (bid >= 1610) {
        int t0 = (bid - 1610) * 256 + threadIdx.x;   // [0, 32768)
        {   // W1: K=128, Nc=256
            int n = t0 & 255, k = t0 >> 8;
            int frag = (n >> 4) * 4 + (k >> 5);
            int lane = ((k >> 3) & 3) * 16 + (n & 15);
            int j = k & 7;
            B2sw[((size_t)frag * 64 + lane) * 8 + j] = f2bf(W1[(size_t)k * FFN_HID + n]);
        }
        {   // W2: K=256, Nc=128
            int n = t0 & 127, k = t0 >> 7;
            int frag = (n >> 4) * 8 + (k >> 5);
            int lane = ((k >> 3) & 3) * 16 + (n & 15);
            int j = k & 7;
            B3sw[((size_t)frag * 64 + lane) * 8 + j] = f2bf(W2[(size_t)k * HID + n]);
        }
        return;
    }
    bool isGemm = (bid < 1536) && ((bid % 3) != 2);
    if (!isGemm) {
        int sid = (bid < 1536) ? (bid / 3) : (512 + bid - 1536);
        int t4 = sid * 256 + threadIdx.x;
        if (t4 < N_EDGES / 4) {
            uint4 d4 = *(const uint4*)&dst[t4 * 4];
            uint4 s4 = *(const uint4*)&src[t4 * 4];
            int slot0 = atomicAdd(&cursor[(int)d4.x * CSTR], 1);
            int slot1 = atomicAdd(&cursor[(int)d4.y * CSTR], 1);
            int slot2 = atomicAdd(&cursor[(int)d4.z * CSTR], 1);
            int slot3 = atomicAdd(&cursor[(int)d4.w * CSTR], 1);
            if (slot0 < BKT) ebkt[(size_t)d4.x * BKT + slot0] = (u16)s4.x;
            if (slot1 < BKT) ebkt[(size_t)d4.y * BKT + slot1] = (u16)s4.y;
            if (slot2 < BKT) ebkt[(size_t)d4.z * BKT + slot2] = (u16)s4.z;
            if (slot3 < BKT) ebkt[(size_t)d4.w * BKT + slot3] = (u16)s4.w;
        }
        return;
    }
    int gid = (bid / 3) * 2 + (bid % 3);
    int tid = threadIdx.x, wave = tid >> 6, lane = tid & 63;
    int lrow = lane & 15, lq = lane >> 4;
    // cooperative coalesced staging: whole block streams Wsrc then Wdst
    // (sequential float4), LDS-transposing into the fragment layout.
    #pragma unroll 4
    for (int i = 0; i < 16; i++) {
        int base = (i * 256 + tid) * 4;
        float4 w4 = *(const float4*)(Wsrc + base);
        #pragma unroll
        for (int e = 0; e < 4; e++) {
            int idx = base + e;
            int k = idx >> 7, n = idx & 127;
            float v = (e == 0) ? w4.x : (e == 1) ? w4.y : (e == 2) ? w4.z : w4.w;
            int wv = n >> 6, nt = (n >> 4) & 3, ks = k >> 5;
            int ln = ((k >> 3) & 3) * 16 + (n & 15);
            bs[wv][nt * 4 + ks][ln * 8 + (k & 7)] = f2bf(v);
        }
    }
    #pragma unroll 4
    for (int i = 0; i < 16; i++) {
        int base = (i * 256 + tid) * 4;
        float4 w4 = *(const float4*)(Wdst + base);
        #pragma unroll
        for (int e = 0; e < 4; e++) {
            int idx = base + e;
            int k = idx >> 7, n = idx & 127;
            float v = (e == 0) ? w4.x : (e == 1) ? w4.y : (e == 2) ? w4.z : w4.w;
            int wv = 2 + (n >> 6), nt = (n >> 4) & 3, ks = k >> 5;
            int ln = ((k >> 3) & 3) * 16 + (n & 15);
            bs[wv][nt * 4 + ks][ln * 8 + (k & 7)] = f2bf(v);
        }
    }
    float bias[4];
    #pragma unroll
    for (int nt = 0; nt < 4; nt++) {
        int cg = wave * 64 + nt * 16 + lrow;
        bias[nt] = (cg < HID) ? bsrc[cg] : bdst[cg - HID];
    }
    __syncthreads();   // staging is cross-wave
    for (int mb = gid; mb < N_NODES / 16; mb += 1024) {
        int m0 = mb * 16;
        const float* hrow = h + (size_t)(m0 + lrow) * HID;
        floatx4 acc[4];
        #pragma unroll
        for (int nt = 0; nt < 4; nt++) acc[nt] = {0.f, 0.f, 0.f, 0.f};
        #pragma unroll
        for (int ks = 0; ks < 4; ks++) {
            float4 va = *(const float4*)(hrow + ks * 32 + lq * 8);
            float4 vb = *(const float4*)(hrow + ks * 32 + lq * 8 + 4);
            short8 a;
            a[0] = (short)f2bf(va.x); a[1] = (short)f2bf(va.y);
            a[2] = (short)f2bf(va.z); a[3] = (short)f2bf(va.w);
            a[4] = (short)f2bf(vb.x); a[5] = (short)f2bf(vb.y);
            a[6] = (short)f2bf(vb.z); a[7] = (short)f2bf(vb.w);
            #pragma unroll
            for (int nt = 0; nt < 4; nt++) {
                short8 b = *(const short8*)&bs[wave][nt * 4 + ks][lane * 8];
                acc[nt] = __builtin_amdgcn_mfma_f32_16x16x32_bf16(a, b, acc[nt], 0, 0, 0);
            }
        }
        #pragma unroll
        for (int nt = 0; nt < 4; nt++) {
            int cg = wave * 64 + nt * 16 + lrow;      // wave-uniform branch per (wave,nt)
            u16* outp = (cg < HID) ? fsb : fdb;
            int c = cg & (HID - 1);
            #pragma unroll
            for (int r = 0; r < 4; r++) {
                int row = m0 + lq * 4 + r;
                outp[(size_t)row * HID + c] = f2bf(acc[nt][r] + bias[nt]);
            }
        }
    }
}

// ---------------- aggregation + residual + LN1 ----------------
// fs, fd gathered/streamed bf16; h residual f32. Emits h1 ONCE as bf16.
// Gather loop software-pipelined (3-buffer rotation, depth-2 prefetch).

__global__ __launch_bounds__(256) void aggregate_kernel(
    const u16* __restrict__ fsb, const u16* __restrict__ fdb,
    const float* __restrict__ h, const float* __restrict__ attn,
    const int* __restrict__ cursor, const u16* __restrict__ ebkt,
    const float* __restrict__ g1, const float* __restrict__ beta1,
    u16* __restrict__ h1b)
{
    int wave = threadIdx.x >> 6, lane = threadIdx.x & 63;
    int node = blockIdx.x * 4 + wave;
    if (node >= N_NODES) return;
    int grp = lane >> 4, fl = lane & 15;
    int f = fl * 8;

    uint4 ud = *(const uint4*)&fdb[(size_t)node * HID + f];
    float fdv[8] = { bflo(ud.x), bfhi(ud.x), bflo(ud.y), bfhi(ud.y),
                     bflo(ud.z), bfhi(ud.z), bflo(ud.w), bfhi(ud.w) };
    float4 aA = *(const float4*)&attn[f];
    float4 aB = *(const float4*)&attn[f + 4];
    float c1[8] = { 0.6f * aA.x, 0.6f * aA.y, 0.6f * aA.z, 0.6f * aA.w,
                    0.6f * aB.x, 0.6f * aB.y, 0.6f * aB.z, 0.6f * aB.w };
    float c2[8] = { 0.4f * aA.x, 0.4f * aA.y, 0.4f * aA.z, 0.4f * aA.w,
                    0.4f * aB.x, 0.4f * aB.y, 0.4f * aB.z, 0.4f * aB.w };

    int cnt = cursor[node * CSTR]; cnt = cnt < BKT ? cnt : BKT;
    const u16* brow = ebkt + (size_t)node * BKT;
    float acc[8] = {0.f, 0.f, 0.f, 0.f, 0.f, 0.f, 0.f, 0.f};
    float lsum = 0.f;

    auto loadrow = [&](int e) -> uint4 {
        int s = (int)brow[e];
        return *(const uint4*)&fsb[(size_t)s * HID + f];
    };
    auto compute = [&](uint4 u) {
        float x[8] = { bflo(u.x), bfhi(u.x), bflo(u.y), bfhi(u.y),
                       bflo(u.z), bfhi(u.z), bflo(u.w), bfhi(u.w) };
        float p = 0.f;
        #pragma unroll
        for (int i = 0; i < 8; i++) {
            float ei = x[i] + fdv[i];
            p = fmaf(c1[i], ei, p);
            p = fmaf(c2[i], fabsf(ei), p);    // fabs folds into fma src modifier
        }
        // head logit: sum over the 4 lanes of this head's quad
        p += __shfl_xor(p, 1); p += __shfl_xor(p, 2);
        float w = __expf(p);
        lsum += w;
        #pragma unroll
        for (int i = 0; i < 8; i++) acc[i] = fmaf(w, x[i], acc[i]);
    };

    // pipelined loop: groups handle edges e = grp, grp+4, grp+8, ...
    {
        int e = grp;
        uint4 bufA, bufB;
        bool vA = (e < cnt), vB = (e + 4 < cnt);
        if (vA) bufA = loadrow(e);
        if (vB) bufB = loadrow(e + 4);
        while (vA) {
            int en = e + 8;
            uint4 bufC; bool vC = (en < cnt);
            if (vC) bufC = loadrow(en);
            compute(bufA);
            bufA = bufB; vA = vB;
            bufB = bufC; vB = vC;
            e += 4;
        }
    }

    // merge the 4 edge-groups (same features, same head per quad)
    #pragma unroll
    for (int i = 0; i < 8; i++) {
        acc[i] += __shfl_xor(acc[i], 16);
        acc[i] += __shfl_xor(acc[i], 32);
    }
    lsum += __shfl_xor(lsum, 16); lsum += __shfl_xor(lsum, 32);

    float inv = (lsum > 0.f) ? (1.0f / lsum) : 0.f;
    float4 h0 = *(const float4*)&h[(size_t)node * HID + f];
    float4 h1v = *(const float4*)&h[(size_t)node * HID + f + 4];
    float hx[8] = { h0.x, h0.y, h0.z, h0.w, h1v.x, h1v.y, h1v.z, h1v.w };
    float o[8], s1 = 0.f, s2 = 0.f;
    #pragma unroll
    for (int i = 0; i < 8; i++) {
        o[i] = hx[i] + acc[i] * inv;
        s1 += o[i]; s2 += o[i] * o[i];
    }
    s1 += __shfl_xor(s1, 1); s2 += __shfl_xor(s2, 1);
    s1 += __shfl_xor(s1, 2); s2 += __shfl_xor(s2, 2);
    s1 += __shfl_xor(s1, 4); s2 += __shfl_xor(s2, 4);
    s1 += __shfl_xor(s1, 8); s2 += __shfl_xor(s2, 8);
    float mu = s1 * (1.0f / HID);
    float var = s2 * (1.0f / HID) - mu * mu;
    float rs = rsqrtf(var + LN_EPS);
    if (grp == 0) {
        float4 gA = *(const float4*)&g1[f], gB = *(const float4*)&g1[f + 4];
        float4 bA = *(const float4*)&beta1[f], bB = *(const float4*)&beta1[f + 4];
        float q0 = (o[0] - mu) * rs * gA.x + bA.x, q1 = (o[1] - mu) * rs * gA.y + bA.y;
        float q2 = (o[2] - mu) * rs * gA.z + bA.z, q3 = (o[3] - mu) * rs * gA.w + bA.w;
        float q4 = (o[4] - mu) * rs * gB.x + bB.x, q5 = (o[5] - mu) * rs * gB.y + bB.y;
        float q6 = (o[6] - mu) * rs * gB.z + bB.z, q7 = (o[7] - mu) * rs * gB.w + bB.w;
        uint4 ob;
        ob.x = packbf(q0, q1); ob.y = packbf(q2, q3);
        ob.z = packbf(q4, q5); ob.w = packbf(q6, q7);
        *(uint4*)&h1b[(size_t)node * HID + f] = ob;
    }
}

// ---------------- fused FFN: out = LN(h1 + gelu(h1@W1+bf1)@W2 + bf2) ----------------
// M=16 structure at 640 blocks; B-fragments from pre-swizzled tables.
// Software prefetch (R17-proven): (a) half of next tile's A issued after
// phase-1 MFMAs; (b) residual loads issued before phase 1.

#define TS_PAD 8   // +8 u16 = 16B: breaks 512B-stride bank pattern on phase-2 ds_read_b128

__global__ __launch_bounds__(256) void ffn_fused(
    const u16* __restrict__ h1b,
    const u16* __restrict__ B2sw, const u16* __restrict__ B3sw,
    const float* __restrict__ bf1, const float* __restrict__ bf2,
    const float* __restrict__ g2, const float* __restrict__ beta2,
    float* __restrict__ out)
{
    __shared__ u16 ts[16][FFN_HID + TS_PAD];
    __shared__ float xs[16][HID];
    int tid = threadIdx.x, wave = tid >> 6, lane = tid & 63;
    int lrow = lane & 15, lq = lane >> 4;

    short8 b1f[4][4];
    #pragma unroll
    for (int nt = 0; nt < 4; nt++)
        #pragma unroll
        for (int ks = 0; ks < 4; ks++) {
            int frag = (wave * 4 + nt) * 4 + ks;
            b1f[nt][ks] = *(const short8*)(B2sw + ((size_t)frag * 64 + lane) * 8);
        }
    short8 b2f[2][8];
    #pragma unroll
    for (int nt = 0; nt < 2; nt++)
        #pragma unroll
        for (int ks = 0; ks < 8; ks++) {
            int frag = (wave * 2 + nt) * 8 + ks;
            b2f[nt][ks] = *(const short8*)(B3sw + ((size_t)frag * 64 + lane) * 8);
        }
    float bias1[4];
    #pragma unroll
    for (int nt = 0; nt < 4; nt++) bias1[nt] = bf1[wave * 64 + nt * 16 + lrow];
    float bias2[2];
    #pragma unroll
    for (int nt = 0; nt < 2; nt++) bias2[nt] = bf2[wave * 32 + nt * 16 + lrow];

    const int NT = N_NODES / 16;
    // prime: half-A prefetch (ks 0,1) for the first tile
    short8 apre0, apre1;
    if (blockIdx.x < NT) {
        const u16* ar = h1b + (size_t)(blockIdx.x * 16 + lrow) * HID + lq * 8;
        apre0 = *(const short8*)(ar);
        apre1 = *(const short8*)(ar + 32);
    }
    for (int mb = blockIdx.x; mb < NT; mb += gridDim.x) {
        int m0 = mb * 16;
        const u16* arow = h1b + (size_t)(m0 + lrow) * HID + lq * 8;
        // (b) early-issue this tile's residual loads (consumed after phase 2)
        u32 rres[8];
        #pragma unroll
        for (int nt = 0; nt < 2; nt++)
            #pragma unroll
            for (int r = 0; r < 4; r++)
                rres[nt * 4 + r] = h1b[(size_t)(m0 + lq * 4 + r) * HID + wave * 32 + nt * 16 + lrow];
        // consume primed A (ks 0,1); load ks 2,3 fresh
        short8 a0 = apre0, a1 = apre1;
        short8 a2 = *(const short8*)(arow + 64);
        short8 a3 = *(const short8*)(arow + 96);
        // ---- phase 1: t = gelu(h1 @ W1 + bf1) into LDS ----
        floatx4 acc1[4];
        #pragma unroll
        for (int nt = 0; nt < 4; nt++) acc1[nt] = {0.f, 0.f, 0.f, 0.f};
        #pragma unroll
        for (int nt = 0; nt < 4; nt++) {
            acc1[nt] = __builtin_amdgcn_mfma_f32_16x16x32_bf16(a0, b1f[nt][0], acc1[nt], 0, 0, 0);
            acc1[nt] = __builtin_amdgcn_mfma_f32_16x16x32_bf16(a1, b1f[nt][1], acc1[nt], 0, 0, 0);
            acc1[nt] = __builtin_amdgcn_mfma_f32_16x16x32_bf16(a2, b1f[nt][2], acc1[nt], 0, 0, 0);
            acc1[nt] = __builtin_amdgcn_mfma_f32_16x16x32_bf16(a3, b1f[nt][3], acc1[nt], 0, 0, 0);
        }
        // (a) issue next tile's half-A prefetch (covered by gelu+barrier+phase2)
        int mbn = mb + gridDim.x;
        if (mbn < NT) {
            const u16* arn = h1b + (size_t)(mbn * 16 + lrow) * HID + lq * 8;
            apre0 = *(const short8*)(arn);
            apre1 = *(const short8*)(arn + 32);
        }
        #pragma unroll
        for (int nt = 0; nt < 4; nt++) {
            int cg = wave * 64 + nt * 16 + lrow;
            #pragma unroll
            for (int r = 0; r < 4; r++) {
                float v = acc1[nt][r] + bias1[nt];
                ts[lq * 4 + r][cg] = f2bf(gelu_fast(v));
            }
        }
        __syncthreads();
        // ---- phase 2: x = t @ W2 + bf2 + h1 (residual pre-loaded in rres) ----
        floatx4 acc2[2];
        #pragma unroll
        for (int nt = 0; nt < 2; nt++) acc2[nt] = {0.f, 0.f, 0.f, 0.f};
        #pragma unroll
        for (int ks = 0; ks < 8; ks++) {
            short8 a = *(const short8*)&ts[lrow][ks * 32 + lq * 8];
            #pragma unroll
            for (int nt = 0; nt < 2; nt++)
                acc2[nt] = __builtin_amdgcn_mfma_f32_16x16x32_bf16(a, b2f[nt][ks], acc2[nt], 0, 0, 0);
        }
        #pragma unroll
        for (int nt = 0; nt < 2; nt++) {
            int cg = wave * 32 + nt * 16 + lrow;
            #pragma unroll
            for (int r = 0; r < 4; r++) {
                float resid = bf2f((u16)rres[nt * 4 + r]);
                xs[lq * 4 + r][cg] = acc2[nt][r] + bias2[nt] + resid;
            }
        }
        __syncthreads();
        // ---- LN + store ----
        int row = tid >> 4, c0 = (tid & 15) * 8;
        float v[8];
        float s1 = 0.f, s2 = 0.f;
        #pragma unroll
        for (int i = 0; i < 8; i++) { v[i] = xs[row][c0 + i]; s1 += v[i]; s2 += v[i] * v[i]; }
        s1 += __shfl_xor(s1, 1); s2 += __shfl_xor(s2, 1);
        s1 += __shfl_xor(s1, 2); s2 += __shfl_xor(s2, 2);
        s1 += __shfl_xor(s1, 4); s2 += __shfl_xor(s2, 4);
        s1 += __shfl_xor(s1, 8); s2 += __shfl_xor(s2, 8);
        float mu = s1 * (1.0f / HID);
        float var = s2 * (1.0f / HID) - mu * mu;
        float rs = rsqrtf(var + LN_EPS);
        float o[8];
        #pragma unroll
        for (int i = 0; i < 8; i++) o[i] = (v[i] - mu) * rs * g2[c0 + i] + beta2[c0 + i];
        float* op = out + (size_t)(m0 + row) * HID + c0;
        *(float4*)(op)     = make_float4(o[0], o[1], o[2], o[3]);
        *(float4*)(op + 4) = make_float4(o[4], o[5], o[6], o[7]);
        __syncthreads();
    }
}

// ---------------- launch ----------------

extern "C" void kernel_launch(void* const* d_in, const int* in_sizes, int n_in,
                              void* d_out, int out_size, void* d_ws, size_t ws_size,
                              hipStream_t stream)
{
    const float* h    = (const float*)d_in[0];
    const int*   src  = (const int*)d_in[1];
    const int*   dst  = (const int*)d_in[2];
    const float* Wsrc = (const float*)d_in[3];
    const float* bsrc = (const float*)d_in[4];
    const float* Wdst = (const float*)d_in[5];
    const float* bdst = (const float*)d_in[6];
    const float* attn = (const float*)d_in[7];
    const float* W1   = (const float*)d_in[8];
    const float* bf1  = (const float*)d_in[9];
    const float* W2   = (const float*)d_in[10];
    const float* bf2  = (const float*)d_in[11];
    const float* g1   = (const float*)d_in[12];
    const float* beta1= (const float*)d_in[13];
    const float* g2   = (const float*)d_in[14];
    const float* beta2= (const float*)d_in[15];
    float* out = (float*)d_out;

    // workspace: fsb/fdb/h1b bf16 (12.8MB each), B2/B3 (64KB each),
    // cursor (3.2MB, 64B-strided), ebkt u16 (6.4MB). ~48MB total.
    u16* fsb = (u16*)d_ws;
    u16* fdb = fsb + (size_t)N_NODES * HID;
    u16* h1b = fdb + (size_t)N_NODES * HID;
    u16* B2 = h1b + (size_t)N_NODES * HID;
    u16* B3 = B2 + 32768;
    int* cursor = (int*)(B3 + 32768);
    u16* ebkt   = (u16*)(cursor + (size_t)N_NODES * CSTR);

    hipMemsetAsync(cursor, 0, (size_t)N_NODES * CSTR * sizeof(int), stream);
    scatter_gemm<<<1738, 256, 0, stream>>>(src, dst, cursor, ebkt,
                                           h, Wsrc, Wdst, bsrc, bdst, fsb, fdb,
                                           W1, W2, B2, B3);
    aggregate_kernel<<<(N_NODES + 3) / 4, 256, 0, stream>>>(fsb, fdb, h, attn, cursor, ebkt, g1, beta1, h1b);
    ffn_fused<<<640, 256, 0, stream>>>(h1b, B2, B3, bf1, bf2, g2, beta2, out);
}

// Round 20
// 204.145 us; speedup vs baseline: 1.0791x; 1.0791x over previous
//
#include <hip/hip_runtime.h>
#include <math.h>

#define N_NODES 50000
#define N_EDGES 600000
#define HID 128
#define FFN_HID 256
#define NEG_SLOPE 0.2f
#define LN_EPS 1e-5f
#define BKT 64            // bucket capacity per node; max degree ~30 for E/N=12 Poisson
#define CSTR 16           // cursor stride (ints): one counter per 64B line

typedef unsigned short u16;
typedef unsigned int u32;
typedef __attribute__((ext_vector_type(8))) short short8;
typedef __attribute__((ext_vector_type(4))) float floatx4;

__device__ __forceinline__ u16 f2bf(float x) {
    unsigned int u = __float_as_uint(x);
    unsigned int r = u + 0x7FFFu + ((u >> 16) & 1u);
    return (u16)(r >> 16);
}
__device__ __forceinline__ float bflo(u32 u) { return __uint_as_float(u << 16); }
__device__ __forceinline__ float bfhi(u32 u) { return __uint_as_float(u & 0xffff0000u); }
__device__ __forceinline__ u32 packbf(float lo, float hi) {
    return (u32)f2bf(lo) | ((u32)f2bf(hi) << 16);
}
__device__ __forceinline__ float bf2f(u16 v) { return __uint_as_float(((u32)v) << 16); }
// tanh-form GELU: max |delta| vs exact erf-GELU ~3e-4; output is bf16-rounded anyway.
__device__ __forceinline__ float gelu_fast(float v) {
    float u = 1.5957691216057308f * fmaf(0.044715f * v * v, v, v);
    return v / (1.0f + __expf(-u));
}

// ---------------- prep: cursor zero + B1 swizzle (replaces hipMemsetAsync) ----------
// blocks [0,3125): zero the strided cursor (800000 ints = 3125*256 exactly)
// blocks [3125,3253): swizzle [Wsrc|Wdst] -> B1 MFMA fragment table (32768 u16)
//   frag = (ng>>4)*4 + (k>>5); lane = ((k>>3)&3)*16 + (ng&15); j = k&7
// This lets scatter_gemm's gemm role fill its LDS fragments with a straight
// contiguous copy (R19 lesson: transposing in-kernel = 15.7M bank conflicts;
// R17 lesson: strided scalar self-swizzle = VMEM-issue tax).

__global__ __launch_bounds__(256) void prep_kernel(
    const float* __restrict__ Wsrc, const float* __restrict__ Wdst,
    int* __restrict__ cursor, u16* __restrict__ B1)
{
    int b = blockIdx.x;
    if (b < 3125) {
        cursor[b * 256 + threadIdx.x] = 0;
        return;
    }
    int t = (b - 3125) * 256 + threadIdx.x;   // [0, 32768)
    const float* W = (t < 16384) ? Wsrc : Wdst;
    int noff = (t < 16384) ? 0 : 128;
    int tt = t & 16383;
    int n = tt & 127, k = tt >> 7;
    int ng = noff + n;
    int frag = (ng >> 4) * 4 + (k >> 5);
    int lane = ((k >> 3) & 3) * 16 + (ng & 15);
    int j = k & 7;
    B1[((size_t)frag * 64 + lane) * 8 + j] = f2bf(W[(size_t)k * HID + n]);
}

// ---------------- co-launched (3 INTERLEAVED roles): scatter + GEMM1 + W-swizzle ----
// grid = 1738 blocks.
//   gemm (1024):    bid<1536 && bid%3!=2, gid=(bid/3)*2+(bid%3)
//   scatter (586):  bid%3==2 (512) + bid in [1536,1610) (74); 4 edges/thread.
//   swizzle (128):  bid>=1610 — W1/W2 -> B2sw/B3sw fragment tables for ffn.
// Gemm B1 fragments: contiguous copy from the pre-swizzled B1 table into
// per-wave-private LDS (16 b128 loads + 16 b128 writes per lane; coalesced,
// conflict-free, no barrier — each wave stages only its own section).

__global__ __launch_bounds__(256) void scatter_gemm(
    const int* __restrict__ src, const int* __restrict__ dst,
    int* __restrict__ cursor, u16* __restrict__ ebkt,
    const float* __restrict__ h, const u16* __restrict__ B1sw,
    const float* __restrict__ bsrc, const float* __restrict__ bdst,
    u16* __restrict__ fsb, u16* __restrict__ fdb,
    const float* __restrict__ W1, const float* __restrict__ W2,
    u16* __restrict__ B2sw, u16* __restrict__ B3sw)
{
    __shared__ u16 bs[4][16][64 * 8];   // [wave][nt*4+ks][lane*8+j] = 64KB (gemm role)
    int bid = blockIdx.x;
    if (bid >= 1610) {
        int t0 = (bid - 1610) * 256 + threadIdx.x;   // [0, 32768)
        {   // W1: K=128, Nc=256
            int n = t0 & 255, k = t0 >> 8;
            int frag = (n >> 4) * 4 + (k >> 5);
            int lane = ((k >> 3) & 3) * 16 + (n & 15);
            int j = k & 7;
            B2sw[((size_t)frag * 64 + lane) * 8 + j] = f2bf(W1[(size_t)k * FFN_HID + n]);
        }
        {   // W2: K=256, Nc=128
            int n = t0 & 127, k = t0 >> 7;
            int frag = (n >> 4) * 8 + (k >> 5);
            int lane = ((k >> 3) & 3) * 16 + (n & 15);
            int j = k & 7;
            B3sw[((size_t)frag * 64 + lane) * 8 + j] = f2bf(W2[(size_t)k * HID + n]);
        }
        return;
    }
    bool isGemm = (bid < 1536) && ((bid % 3) != 2);
    if (!isGemm) {
        int sid = (bid < 1536) ? (bid / 3) : (512 + bid - 1536);
        int t4 = sid * 256 + threadIdx.x;
        if (t4 < N_EDGES / 4) {
            uint4 d4 = *(const uint4*)&dst[t4 * 4];
            uint4 s4 = *(const uint4*)&src[t4 * 4];
            int slot0 = atomicAdd(&cursor[(int)d4.x * CSTR], 1);
            int slot1 = atomicAdd(&cursor[(int)d4.y * CSTR], 1);
            int slot2 = atomicAdd(&cursor[(int)d4.z * CSTR], 1);
            int slot3 = atomicAdd(&cursor[(int)d4.w * CSTR], 1);
            if (slot0 < BKT) ebkt[(size_t)d4.x * BKT + slot0] = (u16)s4.x;
            if (slot1 < BKT) ebkt[(size_t)d4.y * BKT + slot1] = (u16)s4.y;
            if (slot2 < BKT) ebkt[(size_t)d4.z * BKT + slot2] = (u16)s4.z;
            if (slot3 < BKT) ebkt[(size_t)d4.w * BKT + slot3] = (u16)s4.w;
        }
        return;
    }
    int gid = (bid / 3) * 2 + (bid % 3);
    int tid = threadIdx.x, wave = tid >> 6, lane = tid & 63;
    int lrow = lane & 15, lq = lane >> 4;
    // contiguous copy: bs[wave] == B1[wave*8192 .. wave*8192+8191]
    #pragma unroll
    for (int fi = 0; fi < 16; fi++) {
        short8 b = *(const short8*)(B1sw + ((size_t)(wave * 16 + fi) * 64 + lane) * 8);
        *(short8*)&bs[wave][fi][lane * 8] = b;
    }
    float bias[4];
    #pragma unroll
    for (int nt = 0; nt < 4; nt++) {
        int cg = wave * 64 + nt * 16 + lrow;
        bias[nt] = (cg < HID) ? bsrc[cg] : bdst[cg - HID];
    }
    // no __syncthreads: each wave reads only its own bs[wave] section
    for (int mb = gid; mb < N_NODES / 16; mb += 1024) {
        int m0 = mb * 16;
        const float* hrow = h + (size_t)(m0 + lrow) * HID;
        floatx4 acc[4];
        #pragma unroll
        for (int nt = 0; nt < 4; nt++) acc[nt] = {0.f, 0.f, 0.f, 0.f};
        #pragma unroll
        for (int ks = 0; ks < 4; ks++) {
            float4 va = *(const float4*)(hrow + ks * 32 + lq * 8);
            float4 vb = *(const float4*)(hrow + ks * 32 + lq * 8 + 4);
            short8 a;
            a[0] = (short)f2bf(va.x); a[1] = (short)f2bf(va.y);
            a[2] = (short)f2bf(va.z); a[3] = (short)f2bf(va.w);
            a[4] = (short)f2bf(vb.x); a[5] = (short)f2bf(vb.y);
            a[6] = (short)f2bf(vb.z); a[7] = (short)f2bf(vb.w);
            #pragma unroll
            for (int nt = 0; nt < 4; nt++) {
                short8 b = *(const short8*)&bs[wave][nt * 4 + ks][lane * 8];
                acc[nt] = __builtin_amdgcn_mfma_f32_16x16x32_bf16(a, b, acc[nt], 0, 0, 0);
            }
        }
        #pragma unroll
        for (int nt = 0; nt < 4; nt++) {
            int cg = wave * 64 + nt * 16 + lrow;      // wave-uniform branch per (wave,nt)
            u16* outp = (cg < HID) ? fsb : fdb;
            int c = cg & (HID - 1);
            #pragma unroll
            for (int r = 0; r < 4; r++) {
                int row = m0 + lq * 4 + r;
                outp[(size_t)row * HID + c] = f2bf(acc[nt][r] + bias[nt]);
            }
        }
    }
}

// ---------------- aggregation + residual + LN1 ----------------
// fs, fd gathered/streamed bf16; h residual f32. Emits h1 ONCE as bf16.
// Gather loop software-pipelined (3-buffer rotation, depth-2 prefetch).

__global__ __launch_bounds__(256) void aggregate_kernel(
    const u16* __restrict__ fsb, const u16* __restrict__ fdb,
    const float* __restrict__ h, const float* __restrict__ attn,
    const int* __restrict__ cursor, const u16* __restrict__ ebkt,
    const float* __restrict__ g1, const float* __restrict__ beta1,
    u16* __restrict__ h1b)
{
    int wave = threadIdx.x >> 6, lane = threadIdx.x & 63;
    int node = blockIdx.x * 4 + wave;
    if (node >= N_NODES) return;
    int grp = lane >> 4, fl = lane & 15;
    int f = fl * 8;

    uint4 ud = *(const uint4*)&fdb[(size_t)node * HID + f];
    float fdv[8] = { bflo(ud.x), bfhi(ud.x), bflo(ud.y), bfhi(ud.y),
                     bflo(ud.z), bfhi(ud.z), bflo(ud.w), bfhi(ud.w) };
    float4 aA = *(const float4*)&attn[f];
    float4 aB = *(const float4*)&attn[f + 4];
    float c1[8] = { 0.6f * aA.x, 0.6f * aA.y, 0.6f * aA.z, 0.6f * aA.w,
                    0.6f * aB.x, 0.6f * aB.y, 0.6f * aB.z, 0.6f * aB.w };
    float c2[8] = { 0.4f * aA.x, 0.4f * aA.y, 0.4f * aA.z, 0.4f * aA.w,
                    0.4f * aB.x, 0.4f * aB.y, 0.4f * aB.z, 0.4f * aB.w };

    int cnt = cursor[node * CSTR]; cnt = cnt < BKT ? cnt : BKT;
    const u16* brow = ebkt + (size_t)node * BKT;
    float acc[8] = {0.f, 0.f, 0.f, 0.f, 0.f, 0.f, 0.f, 0.f};
    float lsum = 0.f;

    auto loadrow = [&](int e) -> uint4 {
        int s = (int)brow[e];
        return *(const uint4*)&fsb[(size_t)s * HID + f];
    };
    auto compute = [&](uint4 u) {
        float x[8] = { bflo(u.x), bfhi(u.x), bflo(u.y), bfhi(u.y),
                       bflo(u.z), bfhi(u.z), bflo(u.w), bfhi(u.w) };
        float p = 0.f;
        #pragma unroll
        for (int i = 0; i < 8; i++) {
            float ei = x[i] + fdv[i];
            p = fmaf(c1[i], ei, p);
            p = fmaf(c2[i], fabsf(ei), p);    // fabs folds into fma src modifier
        }
        // head logit: sum over the 4 lanes of this head's quad
        p += __shfl_xor(p, 1); p += __shfl_xor(p, 2);
        float w = __expf(p);
        lsum += w;
        #pragma unroll
        for (int i = 0; i < 8; i++) acc[i] = fmaf(w, x[i], acc[i]);
    };

    // pipelined loop: groups handle edges e = grp, grp+4, grp+8, ...
    {
        int e = grp;
        uint4 bufA, bufB;
        bool vA = (e < cnt), vB = (e + 4 < cnt);
        if (vA) bufA = loadrow(e);
        if (vB) bufB = loadrow(e + 4);
        while (vA) {
            int en = e + 8;
            uint4 bufC; bool vC = (en < cnt);
            if (vC) bufC = loadrow(en);
            compute(bufA);
            bufA = bufB; vA = vB;
            bufB = bufC; vB = vC;
            e += 4;
        }
    }

    // merge the 4 edge-groups (same features, same head per quad)
    #pragma unroll
    for (int i = 0; i < 8; i++) {
        acc[i] += __shfl_xor(acc[i], 16);
        acc[i] += __shfl_xor(acc[i], 32);
    }
    lsum += __shfl_xor(lsum, 16); lsum += __shfl_xor(lsum, 32);

    float inv = (lsum > 0.f) ? (1.0f / lsum) : 0.f;
    float4 h0 = *(const float4*)&h[(size_t)node * HID + f];
    float4 h1v = *(const float4*)&h[(size_t)node * HID + f + 4];
    float hx[8] = { h0.x, h0.y, h0.z, h0.w, h1v.x, h1v.y, h1v.z, h1v.w };
    float o[8], s1 = 0.f, s2 = 0.f;
    #pragma unroll
    for (int i = 0; i < 8; i++) {
        o[i] = hx[i] + acc[i] * inv;
        s1 += o[i]; s2 += o[i] * o[i];
    }
    s1 += __shfl_xor(s1, 1); s2 += __shfl_xor(s2, 1);
    s1 += __shfl_xor(s1, 2); s2 += __shfl_xor(s2, 2);
    s1 += __shfl_xor(s1, 4); s2 += __shfl_xor(s2, 4);
    s1 += __shfl_xor(s1, 8); s2 += __shfl_xor(s2, 8);
    float mu = s1 * (1.0f / HID);
    float var = s2 * (1.0f / HID) - mu * mu;
    float rs = rsqrtf(var + LN_EPS);
    if (grp == 0) {
        float4 gA = *(const float4*)&g1[f], gB = *(const float4*)&g1[f + 4];
        float4 bA = *(const float4*)&beta1[f], bB = *(const float4*)&beta1[f + 4];
        float q0 = (o[0] - mu) * rs * gA.x + bA.x, q1 = (o[1] - mu) * rs * gA.y + bA.y;
        float q2 = (o[2] - mu) * rs * gA.z + bA.z, q3 = (o[3] - mu) * rs * gA.w + bA.w;
        float q4 = (o[4] - mu) * rs * gB.x + bB.x, q5 = (o[5] - mu) * rs * gB.y + bB.y;
        float q6 = (o[6] - mu) * rs * gB.z + bB.z, q7 = (o[7] - mu) * rs * gB.w + bB.w;
        uint4 ob;
        ob.x = packbf(q0, q1); ob.y = packbf(q2, q3);
        ob.z = packbf(q4, q5); ob.w = packbf(q6, q7);
        *(uint4*)&h1b[(size_t)node * HID + f] = ob;
    }
}

// ---------------- fused FFN: out = LN(h1 + gelu(h1@W1+bf1)@W2 + bf2) ----------------
// M=16 structure at 640 blocks; B-fragments from pre-swizzled tables.
// Software prefetch (R17-proven): (a) half of next tile's A issued after
// phase-1 MFMAs; (b) residual loads issued before phase 1.

#define TS_PAD 8   // +8 u16 = 16B: breaks 512B-stride bank pattern on phase-2 ds_read_b128

__global__ __launch_bounds__(256) void ffn_fused(
    const u16* __restrict__ h1b,
    const u16* __restrict__ B2sw, const u16* __restrict__ B3sw,
    const float* __restrict__ bf1, const float* __restrict__ bf2,
    const float* __restrict__ g2, const float* __restrict__ beta2,
    float* __restrict__ out)
{
    __shared__ u16 ts[16][FFN_HID + TS_PAD];
    __shared__ float xs[16][HID];
    int tid = threadIdx.x, wave = tid >> 6, lane = tid & 63;
    int lrow = lane & 15, lq = lane >> 4;

    short8 b1f[4][4];
    #pragma unroll
    for (int nt = 0; nt < 4; nt++)
        #pragma unroll
        for (int ks = 0; ks < 4; ks++) {
            int frag = (wave * 4 + nt) * 4 + ks;
            b1f[nt][ks] = *(const short8*)(B2sw + ((size_t)frag * 64 + lane) * 8);
        }
    short8 b2f[2][8];
    #pragma unroll
    for (int nt = 0; nt < 2; nt++)
        #pragma unroll
        for (int ks = 0; ks < 8; ks++) {
            int frag = (wave * 2 + nt) * 8 + ks;
            b2f[nt][ks] = *(const short8*)(B3sw + ((size_t)frag * 64 + lane) * 8);
        }
    float bias1[4];
    #pragma unroll
    for (int nt = 0; nt < 4; nt++) bias1[nt] = bf1[wave * 64 + nt * 16 + lrow];
    float bias2[2];
    #pragma unroll
    for (int nt = 0; nt < 2; nt++) bias2[nt] = bf2[wave * 32 + nt * 16 + lrow];

    const int NT = N_NODES / 16;
    // prime: half-A prefetch (ks 0,1) for the first tile
    short8 apre0, apre1;
    if (blockIdx.x < NT) {
        const u16* ar = h1b + (size_t)(blockIdx.x * 16 + lrow) * HID + lq * 8;
        apre0 = *(const short8*)(ar);
        apre1 = *(const short8*)(ar + 32);
    }
    for (int mb = blockIdx.x; mb < NT; mb += gridDim.x) {
        int m0 = mb * 16;
        const u16* arow = h1b + (size_t)(m0 + lrow) * HID + lq * 8;
        // (b) early-issue this tile's residual loads (consumed after phase 2)
        u32 rres[8];
        #pragma unroll
        for (int nt = 0; nt < 2; nt++)
            #pragma unroll
            for (int r = 0; r < 4; r++)
                rres[nt * 4 + r] = h1b[(size_t)(m0 + lq * 4 + r) * HID + wave * 32 + nt * 16 + lrow];
        // consume primed A (ks 0,1); load ks 2,3 fresh
        short8 a0 = apre0, a1 = apre1;
        short8 a2 = *(const short8*)(arow + 64);
        short8 a3 = *(const short8*)(arow + 96);
        // ---- phase 1: t = gelu(h1 @ W1 + bf1) into LDS ----
        floatx4 acc1[4];
        #pragma unroll
        for (int nt = 0; nt < 4; nt++) acc1[nt] = {0.f, 0.f, 0.f, 0.f};
        #pragma unroll
        for (int nt = 0; nt < 4; nt++) {
            acc1[nt] = __builtin_amdgcn_mfma_f32_16x16x32_bf16(a0, b1f[nt][0], acc1[nt], 0, 0, 0);
            acc1[nt] = __builtin_amdgcn_mfma_f32_16x16x32_bf16(a1, b1f[nt][1], acc1[nt], 0, 0, 0);
            acc1[nt] = __builtin_amdgcn_mfma_f32_16x16x32_bf16(a2, b1f[nt][2], acc1[nt], 0, 0, 0);
            acc1[nt] = __builtin_amdgcn_mfma_f32_16x16x32_bf16(a3, b1f[nt][3], acc1[nt], 0, 0, 0);
        }
        // (a) issue next tile's half-A prefetch (covered by gelu+barrier+phase2)
        int mbn = mb + gridDim.x;
        if (mbn < NT) {
            const u16* arn = h1b + (size_t)(mbn * 16 + lrow) * HID + lq * 8;
            apre0 = *(const short8*)(arn);
            apre1 = *(const short8*)(arn + 32);
        }
        #pragma unroll
        for (int nt = 0; nt < 4; nt++) {
            int cg = wave * 64 + nt * 16 + lrow;
            #pragma unroll
            for (int r = 0; r < 4; r++) {
                float v = acc1[nt][r] + bias1[nt];
                ts[lq * 4 + r][cg] = f2bf(gelu_fast(v));
            }
        }
        __syncthreads();
        // ---- phase 2: x = t @ W2 + bf2 + h1 (residual pre-loaded in rres) ----
        floatx4 acc2[2];
        #pragma unroll
        for (int nt = 0; nt < 2; nt++) acc2[nt] = {0.f, 0.f, 0.f, 0.f};
        #pragma unroll
        for (int ks = 0; ks < 8; ks++) {
            short8 a = *(const short8*)&ts[lrow][ks * 32 + lq * 8];
            #pragma unroll
            for (int nt = 0; nt < 2; nt++)
                acc2[nt] = __builtin_amdgcn_mfma_f32_16x16x32_bf16(a, b2f[nt][ks], acc2[nt], 0, 0, 0);
        }
        #pragma unroll
        for (int nt = 0; nt < 2; nt++) {
            int cg = wave * 32 + nt * 16 + lrow;
            #pragma unroll
            for (int r = 0; r < 4; r++) {
                float resid = bf2f((u16)rres[nt * 4 + r]);
                xs[lq * 4 + r][cg] = acc2[nt][r] + bias2[nt] + resid;
            }
        }
        __syncthreads();
        // ---- LN + store ----
        int row = tid >> 4, c0 = (tid & 15) * 8;
        float v[8];
        float s1 = 0.f, s2 = 0.f;
        #pragma unroll
        for (int i = 0; i < 8; i++) { v[i] = xs[row][c0 + i]; s1 += v[i]; s2 += v[i] * v[i]; }
        s1 += __shfl_xor(s1, 1); s2 += __shfl_xor(s2, 1);
        s1 += __shfl_xor(s1, 2); s2 += __shfl_xor(s2, 2);
        s1 += __shfl_xor(s1, 4); s2 += __shfl_xor(s2, 4);
        s1 += __shfl_xor(s1, 8); s2 += __shfl_xor(s2, 8);
        float mu = s1 * (1.0f / HID);
        float var = s2 * (1.0f / HID) - mu * mu;
        float rs = rsqrtf(var + LN_EPS);
        float o[8];
        #pragma unroll
        for (int i = 0; i < 8; i++) o[i] = (v[i] - mu) * rs * g2[c0 + i] + beta2[c0 + i];
        float* op = out + (size_t)(m0 + row) * HID + c0;
        *(float4*)(op)     = make_float4(o[0], o[1], o[2], o[3]);
        *(float4*)(op + 4) = make_float4(o[4], o[5], o[6], o[7]);
        __syncthreads();
    }
}

// ---------------- launch ----------------

extern "C" void kernel_launch(void* const* d_in, const int* in_sizes, int n_in,
                              void* d_out, int out_size, void* d_ws, size_t ws_size,
                              hipStream_t stream)
{
    const float* h    = (const float*)d_in[0];
    const int*   src  = (const int*)d_in[1];
    const int*   dst  = (const int*)d_in[2];
    const float* Wsrc = (const float*)d_in[3];
    const float* bsrc = (const float*)d_in[4];
    const float* Wdst = (const float*)d_in[5];
    const float* bdst = (const float*)d_in[6];
    const float* attn = (const float*)d_in[7];
    const float* W1   = (const float*)d_in[8];
    const float* bf1  = (const float*)d_in[9];
    const float* W2   = (const float*)d_in[10];
    const float* bf2  = (const float*)d_in[11];
    const float* g1   = (const float*)d_in[12];
    const float* beta1= (const float*)d_in[13];
    const float* g2   = (const float*)d_in[14];
    const float* beta2= (const float*)d_in[15];
    float* out = (float*)d_out;

    // workspace: fsb/fdb/h1b bf16 (12.8MB each), B1/B2/B3 (64KB each),
    // cursor (3.2MB, 64B-strided), ebkt u16 (6.4MB). ~48MB total.
    u16* fsb = (u16*)d_ws;
    u16* fdb = fsb + (size_t)N_NODES * HID;
    u16* h1b = fdb + (size_t)N_NODES * HID;
    u16* B1 = h1b + (size_t)N_NODES * HID;
    u16* B2 = B1 + 32768;
    u16* B3 = B2 + 32768;
    int* cursor = (int*)(B3 + 32768);
    u16* ebkt   = (u16*)(cursor + (size_t)N_NODES * CSTR);

    prep_kernel<<<3253, 256, 0, stream>>>(Wsrc, Wdst, cursor, B1);
    scatter_gemm<<<1738, 256, 0, stream>>>(src, dst, cursor, ebkt,
                                           h, B1, bsrc, bdst, fsb, fdb,
                                           W1, W2, B2, B3);
    aggregate_kernel<<<(N_NODES + 3) / 4, 256, 0, stream>>>(fsb, fdb, h, attn, cursor, ebkt, g1, beta1, h1b);
    ffn_fused<<<640, 256, 0, stream>>>(h1b, B2, B3, bf1, bf2, g2, beta2, out);
}